// Round 14
// baseline (230.182 us; speedup 1.0000x reference)
//
#include <hip/hip_runtime.h>
#include <math.h>

#define NB1 8192
#define NB2 12288
#define DD  128

typedef unsigned long long u64;
typedef unsigned short ushort_t;
typedef __attribute__((ext_vector_type(8))) short short8;
typedef __attribute__((ext_vector_type(8))) _Float16 half8;
typedef __attribute__((ext_vector_type(4))) float f32x4;

__device__ __forceinline__ float bigf() { return __uint_as_float(0x7F7F0000u); }
__device__ __forceinline__ u64 umin64(u64 a, u64 b) { return a < b ? a : b; }
__device__ __forceinline__ unsigned umin32(unsigned a, unsigned b) { return a < b ? a : b; }

__device__ __forceinline__ ushort_t bf_rn(float x) {
    unsigned u = __float_as_uint(x);
    return (ushort_t)((u + 0x7FFFu + ((u >> 16) & 1u)) >> 16);
}
__device__ __forceinline__ float bf_up(ushort_t h) {
    return __uint_as_float(((unsigned)h) << 16);
}
__device__ __forceinline__ int fswz(int r) { return (r + (r >> 2)) & 3; }
__device__ __forceinline__ half8 ld8h(const _Float16* p) { return *(const half8*)p; }

// Kernel N: squared norms + init packed min arrays.
__global__ __launch_bounds__(256) void prep_kernel(
    const float* __restrict__ d1, const float* __restrict__ d2,
    float* __restrict__ sq1, float* __restrict__ sq2,
    u64* __restrict__ rowmin, u64* __restrict__ colmin) {
    int t = blockIdx.x * 256 + threadIdx.x;
    if (t < NB1) {
        rowmin[t] = ~0ull;
        const float4* p = (const float4*)(d1 + (size_t)t * DD);
        float s = 0.f;
        #pragma unroll
        for (int c = 0; c < DD / 4; ++c) {
            float4 v = p[c];
            s = fmaf(v.x, v.x, s); s = fmaf(v.y, v.y, s);
            s = fmaf(v.z, v.z, s); s = fmaf(v.w, v.w, s);
        }
        sq1[t] = s;
    }
    if (t < NB2) {
        colmin[t] = ~0ull;
        const float4* p = (const float4*)(d2 + (size_t)t * DD);
        float s = 0.f;
        #pragma unroll
        for (int c = 0; c < DD / 4; ++c) {
            float4 v = p[c];
            s = fmaf(v.x, v.x, s); s = fmaf(v.y, v.y, s);
            s = fmaf(v.z, v.z, s); s = fmaf(v.w, v.w, s);
        }
        sq2[t] = s;
    }
}

// Kernel SE: 2-way f16 split into K-CONCATENATED fragment-major planes.
// Extended rows (K_eff = 384 = 12 k-chunks of 32):
//   A' = [ H | M~ | H~ ]   B' = [ H' | H~' | M~' ]
// with H = f16(x), m = x - H (exact), M~ = f16(2^8 m), H~ = f16(2^-8 H).
// GEMM over K=384 yields  Sum hh' + Sum mh' + Sum hm'  in ONE chain.
__global__ __launch_bounds__(256) void split_ext16_kernel(
    const float* __restrict__ d1, const float* __restrict__ d2,
    _Float16* __restrict__ Af, _Float16* __restrict__ Bf) {
    int t = blockIdx.x * 256 + threadIdx.x;    // 0 .. 983039
    int lane = t & 63;
    int task = t >> 6;                          // 0 .. 15359
    bool isA = task < 6144;
    int lt = isA ? task : task - 6144;
    int rb = lt / 12;
    int kc = lt - rb * 12;
    int region = kc >> 2;                       // 0:H, then side-specific
    int row = rb * 16 + (lane & 15);
    int kst = (kc & 3) * 32 + (lane >> 4) * 8;
    const float* src = (isA ? d1 : d2) + (size_t)row * DD + kst;
    _Float16* dst = (isA ? Af : Bf) + ((size_t)lt * 512 + lane * 8);

    // A regions: 0->H, 1->M~, 2->H~.  B regions: 0->H, 1->H~, 2->M~.
    bool wantM = isA ? (region == 1) : (region == 2);
    half8 V;
    #pragma unroll
    for (int e = 0; e < 8; ++e) {
        float x = src[e];
        _Float16 hf = (_Float16)x;
        float h = (float)hf;
        float v;
        if (region == 0)      v = x;                       // f16(x) on store
        else if (wantM)       v = (x - h) * 256.0f;        // M~ = 2^8 m
        else                  v = h * 0.00390625f;         // H~ = 2^-8 h
        V[e] = (_Float16)v;
    }
    *(half8*)dst = V;
}

// Kernel T8: barrier-free f16 MFMA distance tiles (round-13 loop) with a
// CHEAP epilogue: f32 tracked argmin (strict <, ascending index = exact
// first-occurrence), value-only butterflies, and dist^2 (>= 0, so raw IEEE
// bits are u32-monotone) packed u64 only at the final reduced level.
__global__ __launch_bounds__(256) void mfma_tile8_kernel(
    const _Float16* __restrict__ Af, const _Float16* __restrict__ Bf,
    const float* __restrict__ sq1, const float* __restrict__ sq2,
    u64* __restrict__ rowmin, u64* __restrict__ colmin)
{
    const int bid  = blockIdx.x;
    const int xcd  = bid & 7;
    const int t_   = bid >> 3;          // 0..767 per xcd
    const int kch  = t_ >> 6;           // 0..11  j-chunk index
    const int wdn  = t_ & 63;
    const int j0b  = (kch * 8 + (wdn & 7)) * 128;
    const int i0b  = (xcd * 8 + (wdn >> 3)) * 128;

    const int tid  = threadIdx.x;
    const int lane = tid & 63;
    const int wid  = tid >> 6;
    const int wr   = wid >> 1;
    const int wc   = wid & 1;
    const int lrow = lane & 15;
    const int lg   = lane >> 4;

    // Tile (rb, kc) at rb*6144 + kc*512 f16 (rb stride = 12 kc x 512).
    const _Float16* abase = Af + ((size_t)((i0b >> 4) + wr * 4) * 6144) + lane * 8;
    const _Float16* bbase = Bf + ((size_t)((j0b >> 4) + wc * 4) * 6144) + lane * 8;

    f32x4 acc[4][4];
    #pragma unroll
    for (int mi = 0; mi < 4; ++mi)
        #pragma unroll
        for (int ni = 0; ni < 4; ++ni)
            acc[mi][ni] = (f32x4){0.f, 0.f, 0.f, 0.f};

    #pragma unroll 1
    for (int kc = 0; kc < 12; ++kc) {
        const int ko = kc * 512;
        half8 bfr[4];
        #pragma unroll
        for (int ni = 0; ni < 4; ++ni)
            bfr[ni] = ld8h(bbase + ni * 6144 + ko);
        half8 a0, a1;
        a0 = ld8h(abase + ko);
        #pragma unroll
        for (int mi = 0; mi < 4; ++mi) {
            if (mi < 3)
                a1 = ld8h(abase + (mi + 1) * 6144 + ko);
            #pragma unroll
            for (int ni = 0; ni < 4; ++ni)
                acc[mi][ni] = __builtin_amdgcn_mfma_f32_16x16x32_f16(a0, bfr[ni], acc[mi][ni], 0, 0, 0);
            a0 = a1;
        }
    }

    // ---- epilogue ----
    // C/D: row = i0b + wr*64 + mi*16 + 4*lg + r, col = j0b + wc*64 + ni*16 + lrow.
    float q2v[4];
    #pragma unroll
    for (int ni = 0; ni < 4; ++ni)
        q2v[ni] = sq2[j0b + wc * 64 + ni * 16 + lrow];
    float4 q1v[4];
    #pragma unroll
    for (int mi = 0; mi < 4; ++mi)
        q1v[mi] = *(const float4*)(sq1 + i0b + wr * 64 + mi * 16 + 4 * lg);

    // Col tracked state (per ni): min of (q1[i] - 2d) over in-thread i's.
    float    cmin[4];
    unsigned cidx[4];
    #pragma unroll
    for (int ni = 0; ni < 4; ++ni) { cmin[ni] = __uint_as_float(0x7F800000u); cidx[ni] = 0xFFFFFFFFu; }

    #pragma unroll
    for (int mi = 0; mi < 4; ++mi) {
        const float* q1p = (const float*)&q1v[mi];
        #pragma unroll
        for (int r = 0; r < 4; ++r) {
            const float    q1 = q1p[r];
            const unsigned irow = (unsigned)(i0b + wr * 64 + mi * 16 + 4 * lg + r);
            // Row tracked over ni (ascending; strict < keeps first occurrence).
            float    rbest = 0.f;
            unsigned rbn = 0;
            #pragma unroll
            for (int ni = 0; ni < 4; ++ni) {
                float d = acc[mi][ni][r];
                float t = fmaf(-2.f, d, q2v[ni]);       // row key (q1 const)
                float c = fmaf(-2.f, d, q1);            // col key (q2 const)
                if (ni == 0) { rbest = t; }
                else if (t < rbest) { rbest = t; rbn = (unsigned)ni; }
                if (c < cmin[ni]) { cmin[ni] = c; cidx[ni] = irow; }
            }
            // Value butterfly over the 16-lane group (same row i).
            float g = rbest;
            #pragma unroll
            for (int mask = 8; mask; mask >>= 1)
                g = fminf(g, __shfl_xor(g, mask));
            unsigned jc = (rbest == g)
                ? (unsigned)(j0b + wc * 64 + rbn * 16 + lrow) : 0xFFFFFFFFu;
            #pragma unroll
            for (int mask = 8; mask; mask >>= 1)
                jc = umin32(jc, (unsigned)__shfl_xor((int)jc, mask));
            if (lrow == 0) {
                float d2 = g + q1;                      // dist^2 >= 0
                u64 pk = ((u64)__float_as_uint(d2) << 32) | jc;
                atomicMin(&rowmin[irow], pk);
            }
        }
    }

    // Col finalize: pack dist^2 + i, merge the 4 lane groups (xor 16, 32).
    #pragma unroll
    for (int ni = 0; ni < 4; ++ni) {
        float d2 = cmin[ni] + q2v[ni];                  // dist^2 >= 0
        u64 pk = ((u64)__float_as_uint(d2) << 32) | cidx[ni];
        pk = umin64(pk, __shfl_xor(pk, 16));
        pk = umin64(pk, __shfl_xor(pk, 32));
        if (lane < 16)
            atomicMin(&colmin[j0b + wc * 64 + ni * 16 + lrow], pk);
    }
}

// ============================ fallback path ============================
// In-kernel bf16 3-way split LDS version; epilogue uses the same
// dist^2-bits packing so it shares final_kernel semantics.
__global__ __launch_bounds__(256) void mfma_tile_kernel(
    const float* __restrict__ d1, const float* __restrict__ d2,
    const float* __restrict__ sq1, const float* __restrict__ sq2,
    u64* __restrict__ rowmin, u64* __restrict__ colmin)
{
    __shared__ __align__(16) short lds[6 * 4096];
    const int tid = threadIdx.x;
    const int i0b = blockIdx.y * 128;
    const int j0b = blockIdx.x * 128;
    const int srow  = tid >> 1;
    const int shalf = tid & 1;
    const int sfr   = fswz(srow);
    const int sg0   = ((2 * shalf) ^ sfr) * 8;
    const int sg1   = ((2 * shalf + 1) ^ sfr) * 8;
    const float* gA = d1 + (size_t)(i0b + srow) * DD + shalf * 16;
    const float* gB = d2 + (size_t)(j0b + srow) * DD + shalf * 16;
    short* wA = lds + srow * 32;
    short* wB = lds + 3 * 4096 + srow * 32;
    const int lane = tid & 63;
    const int wid  = tid >> 6;
    const int wr   = wid >> 1;
    const int wc   = wid & 1;
    const int lrow = lane & 15;
    const int lg   = lane >> 4;
    const int gx   = (lg ^ fswz(lrow)) * 8;
    const int aoff = (wr * 64 + lrow) * 32 + gx;
    const int boff = 3 * 4096 + (wc * 64 + lrow) * 32 + gx;

    f32x4 acc[4][4];
    #pragma unroll
    for (int mi = 0; mi < 4; ++mi)
        #pragma unroll
        for (int ni = 0; ni < 4; ++ni)
            acc[mi][ni] = (f32x4){0.f, 0.f, 0.f, 0.f};

    for (int kc = 0; kc < 4; ++kc) {
        {
            const float* sp = gA + kc * 32;
            short8 H0, M0, L0, H1, M1, L1;
            #pragma unroll
            for (int e = 0; e < 8; ++e) {
                float x = sp[e];
                ushort_t h = bf_rn(x); float r1 = x - bf_up(h);
                ushort_t m = bf_rn(r1); float r2 = r1 - bf_up(m);
                H0[e] = (short)h; M0[e] = (short)m; L0[e] = (short)bf_rn(r2);
            }
            #pragma unroll
            for (int e = 0; e < 8; ++e) {
                float x = sp[8 + e];
                ushort_t h = bf_rn(x); float r1 = x - bf_up(h);
                ushort_t m = bf_rn(r1); float r2 = r1 - bf_up(m);
                H1[e] = (short)h; M1[e] = (short)m; L1[e] = (short)bf_rn(r2);
            }
            *(short8*)(wA + sg0)        = H0;
            *(short8*)(wA + sg1)        = H1;
            *(short8*)(wA + 4096 + sg0) = M0;
            *(short8*)(wA + 4096 + sg1) = M1;
            *(short8*)(wA + 8192 + sg0) = L0;
            *(short8*)(wA + 8192 + sg1) = L1;
        }
        {
            const float* sp = gB + kc * 32;
            short8 H0, M0, L0, H1, M1, L1;
            #pragma unroll
            for (int e = 0; e < 8; ++e) {
                float x = sp[e];
                ushort_t h = bf_rn(x); float r1 = x - bf_up(h);
                ushort_t m = bf_rn(r1); float r2 = r1 - bf_up(m);
                H0[e] = (short)h; M0[e] = (short)m; L0[e] = (short)bf_rn(r2);
            }
            #pragma unroll
            for (int e = 0; e < 8; ++e) {
                float x = sp[8 + e];
                ushort_t h = bf_rn(x); float r1 = x - bf_up(h);
                ushort_t m = bf_rn(r1); float r2 = r1 - bf_up(m);
                H1[e] = (short)h; M1[e] = (short)m; L1[e] = (short)bf_rn(r2);
            }
            *(short8*)(wB + sg0)        = H0;
            *(short8*)(wB + sg1)        = H1;
            *(short8*)(wB + 4096 + sg0) = M0;
            *(short8*)(wB + 4096 + sg1) = M1;
            *(short8*)(wB + 8192 + sg0) = L0;
            *(short8*)(wB + 8192 + sg1) = L1;
        }
        __syncthreads();
        short8 af[3][4], bfr[3][4];
        #pragma unroll
        for (int c = 0; c < 3; ++c)
            #pragma unroll
            for (int t = 0; t < 4; ++t) {
                af[c][t]  = *(const short8*)(lds + c * 4096 + aoff + t * 512);
                bfr[c][t] = *(const short8*)(lds + c * 4096 + boff + t * 512);
            }
        #pragma unroll
        for (int mi = 0; mi < 4; ++mi)
            #pragma unroll
            for (int ni = 0; ni < 4; ++ni) {
                f32x4 a = acc[mi][ni];
                a = __builtin_amdgcn_mfma_f32_16x16x32_bf16(af[0][mi], bfr[0][ni], a, 0, 0, 0);
                a = __builtin_amdgcn_mfma_f32_16x16x32_bf16(af[0][mi], bfr[1][ni], a, 0, 0, 0);
                a = __builtin_amdgcn_mfma_f32_16x16x32_bf16(af[1][mi], bfr[0][ni], a, 0, 0, 0);
                a = __builtin_amdgcn_mfma_f32_16x16x32_bf16(af[0][mi], bfr[2][ni], a, 0, 0, 0);
                a = __builtin_amdgcn_mfma_f32_16x16x32_bf16(af[1][mi], bfr[1][ni], a, 0, 0, 0);
                a = __builtin_amdgcn_mfma_f32_16x16x32_bf16(af[2][mi], bfr[0][ni], a, 0, 0, 0);
                acc[mi][ni] = a;
            }
        __syncthreads();
    }

    float q2v[4];
    #pragma unroll
    for (int ni = 0; ni < 4; ++ni)
        q2v[ni] = sq2[j0b + wc * 64 + ni * 16 + lrow];
    float4 q1v[4];
    #pragma unroll
    for (int mi = 0; mi < 4; ++mi)
        q1v[mi] = *(const float4*)(sq1 + i0b + wr * 64 + mi * 16 + 4 * lg);

    float    cmin[4];
    unsigned cidx[4];
    #pragma unroll
    for (int ni = 0; ni < 4; ++ni) { cmin[ni] = __uint_as_float(0x7F800000u); cidx[ni] = 0xFFFFFFFFu; }

    #pragma unroll
    for (int mi = 0; mi < 4; ++mi) {
        const float* q1p = (const float*)&q1v[mi];
        #pragma unroll
        for (int r = 0; r < 4; ++r) {
            const float    q1 = q1p[r];
            const unsigned irow = (unsigned)(i0b + wr * 64 + mi * 16 + 4 * lg + r);
            float    rbest = 0.f;
            unsigned rbn = 0;
            #pragma unroll
            for (int ni = 0; ni < 4; ++ni) {
                float d = acc[mi][ni][r];
                float t = fmaf(-2.f, d, q2v[ni]);
                float c = fmaf(-2.f, d, q1);
                if (ni == 0) { rbest = t; }
                else if (t < rbest) { rbest = t; rbn = (unsigned)ni; }
                if (c < cmin[ni]) { cmin[ni] = c; cidx[ni] = irow; }
            }
            float g = rbest;
            #pragma unroll
            for (int mask = 8; mask; mask >>= 1)
                g = fminf(g, __shfl_xor(g, mask));
            unsigned jc = (rbest == g)
                ? (unsigned)(j0b + wc * 64 + rbn * 16 + lrow) : 0xFFFFFFFFu;
            #pragma unroll
            for (int mask = 8; mask; mask >>= 1)
                jc = umin32(jc, (unsigned)__shfl_xor((int)jc, mask));
            if (lrow == 0) {
                float d2 = g + q1;
                u64 pk = ((u64)__float_as_uint(d2) << 32) | jc;
                atomicMin(&rowmin[irow], pk);
            }
        }
    }
    #pragma unroll
    for (int ni = 0; ni < 4; ++ni) {
        float d2 = cmin[ni] + q2v[ni];
        u64 pk = ((u64)__float_as_uint(d2) << 32) | cidx[ni];
        pk = umin64(pk, __shfl_xor(pk, 16));
        pk = umin64(pk, __shfl_xor(pk, 32));
        if (lane < 16)
            atomicMin(&colmin[j0b + wc * 64 + ni * 16 + lrow], pk);
    }
}

// Kernel 3: assemble outputs. rowmin/colmin hold (dist^2 bits << 32) | idx.
// Non-mutual rows get bigf() instead of +inf (inf-inf = NaN fails diff).
__global__ __launch_bounds__(256) void final_kernel(
    const u64* __restrict__ rowmin, const u64* __restrict__ colmin,
    float* __restrict__ out) {
    int i = blockIdx.x * 256 + threadIdx.x;
    if (i >= NB1) return;
    u64 rm = rowmin[i];
    unsigned ju = (unsigned)(rm & 0xFFFFFFFFu);
    float d2 = __uint_as_float((unsigned)(rm >> 32));
    float dist = sqrtf(fmaxf(d2, 0.f));
    dist = fminf(dist, bigf());
    bool valid = (ju < (unsigned)NB2);
    int j = valid ? (int)ju : 0;
    u64 cm = colmin[j];
    int i2 = (int)(cm & 0xFFFFFFFFu);
    bool mut = valid && (i2 == i);
    out[i] = mut ? dist : bigf();
    out[NB1 + 2 * i]     = mut ? (float)i : -1.f;
    out[NB1 + 2 * i + 1] = mut ? (float)j : -1.f;
    out[NB1 + 2 * NB1 + i] = mut ? 1.f : 0.f;
}

extern "C" void kernel_launch(void* const* d_in, const int* in_sizes, int n_in,
                              void* d_out, int out_size, void* d_ws, size_t ws_size,
                              hipStream_t stream) {
    const float* d1 = (const float*)d_in[0];
    const float* d2 = (const float*)d_in[1];
    float* out = (float*)d_out;

    char* ws = (char*)d_ws;
    float* sq1    = (float*)(ws);
    float* sq2    = (float*)(ws + 32768);
    u64*   rowmin = (u64*)(ws + 81920);
    u64*   colmin = (u64*)(ws + 147456);
    _Float16* Af = (_Float16*)(ws + 245760);            // 512*12*512*2  = 6,291,456 B
    _Float16* Bf = (_Float16*)(ws + 245760 + 6291456);  // 768*12*512*2  = 9,437,184 B
    const size_t need = 245760 + 6291456 + 9437184;     // ~15.2 MB

    hipLaunchKernelGGL(prep_kernel, dim3((NB2 + 255) / 256), dim3(256), 0, stream,
                       d1, d2, sq1, sq2, rowmin, colmin);
    if (ws_size >= need) {
        hipLaunchKernelGGL(split_ext16_kernel, dim3(3840), dim3(256), 0, stream,
                           d1, d2, Af, Bf);
        hipLaunchKernelGGL(mfma_tile8_kernel, dim3(6144), dim3(256), 0, stream,
                           Af, Bf, sq1, sq2, rowmin, colmin);
    } else {
        hipLaunchKernelGGL(mfma_tile_kernel, dim3(NB2 / 128, NB1 / 128), dim3(256), 0, stream,
                           d1, d2, sq1, sq2, rowmin, colmin);
    }
    hipLaunchKernelGGL(final_kernel, dim3((NB1 + 255) / 256), dim3(256), 0, stream,
                       rowmin, colmin, out);
}

// Round 15
// 222.505 us; speedup vs baseline: 1.0345x; 1.0345x over previous
//
#include <hip/hip_runtime.h>
#include <math.h>

#define NB1 8192
#define NB2 12288
#define DD  128
#define KE  384          // K-concat: [H | X | Y] regions of 128

typedef unsigned long long u64;
typedef unsigned short ushort_t;
typedef __attribute__((ext_vector_type(8))) short short8;
typedef __attribute__((ext_vector_type(8))) _Float16 half8;
typedef __attribute__((ext_vector_type(4))) float f32x4;

__device__ __forceinline__ float bigf() { return __uint_as_float(0x7F7F0000u); }
__device__ __forceinline__ u64 umin64(u64 a, u64 b) { return a < b ? a : b; }
__device__ __forceinline__ unsigned umin32(unsigned a, unsigned b) { return a < b ? a : b; }

__device__ __forceinline__ ushort_t bf_rn(float x) {
    unsigned u = __float_as_uint(x);
    return (ushort_t)((u + 0x7FFFu + ((u >> 16) & 1u)) >> 16);
}
__device__ __forceinline__ float bf_up(ushort_t h) {
    return __uint_as_float(((unsigned)h) << 16);
}
__device__ __forceinline__ int fswz(int r) { return (r + (r >> 2)) & 3; }
__device__ __forceinline__ half8 ld8h(const _Float16* p) { return *(const half8*)p; }

__device__ __forceinline__ void gload_lds16(const void* g, void* l) {
    __builtin_amdgcn_global_load_lds(
        (const __attribute__((address_space(1))) unsigned*)g,
        (__attribute__((address_space(3))) unsigned*)l, 16, 0, 0);
}

// Kernel N: squared norms + init packed min arrays.
__global__ __launch_bounds__(256) void prep_kernel(
    const float* __restrict__ d1, const float* __restrict__ d2,
    float* __restrict__ sq1, float* __restrict__ sq2,
    u64* __restrict__ rowmin, u64* __restrict__ colmin) {
    int t = blockIdx.x * 256 + threadIdx.x;
    if (t < NB1) {
        rowmin[t] = ~0ull;
        const float4* p = (const float4*)(d1 + (size_t)t * DD);
        float s = 0.f;
        #pragma unroll
        for (int c = 0; c < DD / 4; ++c) {
            float4 v = p[c];
            s = fmaf(v.x, v.x, s); s = fmaf(v.y, v.y, s);
            s = fmaf(v.z, v.z, s); s = fmaf(v.w, v.w, s);
        }
        sq1[t] = s;
    }
    if (t < NB2) {
        colmin[t] = ~0ull;
        const float4* p = (const float4*)(d2 + (size_t)t * DD);
        float s = 0.f;
        #pragma unroll
        for (int c = 0; c < DD / 4; ++c) {
            float4 v = p[c];
            s = fmaf(v.x, v.x, s); s = fmaf(v.y, v.y, s);
            s = fmaf(v.z, v.z, s); s = fmaf(v.w, v.w, s);
        }
        sq2[t] = s;
    }
}

// Kernel SK: 2-way f16 split into ROW-MAJOR K-concat planes (K_eff = 384):
//   A' = [ H | M~ | H~ ]   B' = [ H | H~ | M~ ]
// H = f16(x), m = x - H (exact), M~ = f16(2^8 m), H~ = f16(2^-8 H).
// GEMM over K=384 yields  Sum hh' + Sum mh' + Sum hm'  in ONE chain
// (2^±8 cancels in cross products; scales exact; subnormal H~ correction
// <= 2^-18|h'| per elem, negligible). 4 threads per row, 32 elems each.
__global__ __launch_bounds__(256) void split_kcat16_kernel(
    const float* __restrict__ d1, const float* __restrict__ d2,
    _Float16* __restrict__ Ap, _Float16* __restrict__ Bp) {
    int t = blockIdx.x * 256 + threadIdx.x;    // 0 .. 81919
    int row = t >> 2, q = t & 3;
    bool isA = row < NB1;
    int r = isA ? row : row - NB1;
    const float* src = (isA ? d1 : d2) + (size_t)r * DD + q * 32;
    _Float16* dst = (isA ? Ap : Bp) + (size_t)r * KE + q * 32;

    #pragma unroll
    for (int v = 0; v < 4; ++v) {
        half8 H, S1, S2;
        #pragma unroll
        for (int e = 0; e < 8; ++e) {
            float x = src[v * 8 + e];
            _Float16 hf = (_Float16)x;
            float h = (float)hf;
            _Float16 Mt = (_Float16)((x - h) * 256.0f);
            _Float16 Ht = (_Float16)(h * 0.00390625f);
            H[e] = hf;
            S1[e] = isA ? Mt : Ht;
            S2[e] = isA ? Ht : Mt;
        }
        *(half8*)(dst + v * 8)       = H;
        *(half8*)(dst + 128 + v * 8) = S1;
        *(half8*)(dst + 256 + v * 8) = S2;
    }
}

// Kernel T9: m97-style LDS-staged f16 GEMM tile kernel, fused min-reduce.
// Block 256 = 4 waves (2x2 of 64x64 wave tiles), block tile 128x128,
// 12 K-steps of BK=32. Per K-step: 4 gload_lds(16B)/thread stage A+B
// (16 KiB single buffer) -> barrier -> 8 ds_read_b128 + 16 MFMA -> barrier.
// Each block reads its unique 192 KB exactly once (halves L2 traffic vs
// the barrier-free design); small LDS + low VGPR -> ~4 blocks/CU whose
// waves hide the stage latency (m114 mechanism).
// LDS layout: (row, slot) at byte row*64 + slot*16, slot = g ^ ((row>>1)&3)
// -> ds_read_b128 lands exactly 2 lanes/bank (free). Swizzle realized by
// pre-swizzled GLOBAL source + linear gload_lds dest.
__global__ __launch_bounds__(256) void mfma_lds9_kernel(
    const _Float16* __restrict__ Ap, const _Float16* __restrict__ Bp,
    const float* __restrict__ sq1, const float* __restrict__ sq2,
    u64* __restrict__ rowmin, u64* __restrict__ colmin)
{
    __shared__ __align__(16) _Float16 lds[8192];   // A: [0,4096), B: [4096,8192) f16

    const int bid  = blockIdx.x;
    const int xcd  = bid & 7;
    const int t_   = bid >> 3;
    const int kch  = t_ >> 6;
    const int wdn  = t_ & 63;
    const int j0b  = (kch * 8 + (wdn & 7)) * 128;
    const int i0b  = (xcd * 8 + (wdn >> 3)) * 128;

    const int tid  = threadIdx.x;
    const int lane = tid & 63;
    const int wid  = tid >> 6;
    const int wr   = wid >> 1;
    const int wc   = wid & 1;
    const int lrow = lane & 15;
    const int lg   = lane >> 4;

    // ---- staging geometry (per lane): q in {0,1} halves of 128 rows ----
    const int srow0 = wid * 16 + (lane >> 2);        // rows 0..63
    const int srow1 = 64 + srow0;                    // rows 64..127
    const int g0 = (lane & 3) ^ ((srow0 >> 1) & 3);
    const int g1 = (lane & 3) ^ ((srow1 >> 1) & 3);
    const _Float16* a0src = Ap + (size_t)(i0b + srow0) * KE + g0 * 8;
    const _Float16* a1src = Ap + (size_t)(i0b + srow1) * KE + g1 * 8;
    const _Float16* b0src = Bp + (size_t)(j0b + srow0) * KE + g0 * 8;
    const _Float16* b1src = Bp + (size_t)(j0b + srow1) * KE + g1 * 8;
    char* ldsA0 = (char*)lds + wid * 1024;           // wave-uniform bases
    char* ldsA1 = (char*)lds + 4096 + wid * 1024;
    char* ldsB0 = (char*)lds + 8192 + wid * 1024;
    char* ldsB1 = (char*)lds + 12288 + wid * 1024;

    // ---- read geometry: frag (row, kg=lg) at shorts row*32 + (lg^swz)*8 ----
    const int arow = wr * 64 + lrow;                 // + mi*16 (swz invariant)
    const int brow = wc * 64 + lrow;
    const int aoff = arow * 32 + ((lg ^ ((arow >> 1) & 3)) * 8);        // + mi*512
    const int boff = 4096 + brow * 32 + ((lg ^ ((brow >> 1) & 3)) * 8); // + ni*512

    f32x4 acc[4][4];
    #pragma unroll
    for (int mi = 0; mi < 4; ++mi)
        #pragma unroll
        for (int ni = 0; ni < 4; ++ni)
            acc[mi][ni] = (f32x4){0.f, 0.f, 0.f, 0.f};

    #pragma unroll 1
    for (int T = 0; T < 12; ++T) {
        const int ko = T * 32;
        gload_lds16(a0src + ko, ldsA0);
        gload_lds16(a1src + ko, ldsA1);
        gload_lds16(b0src + ko, ldsB0);
        gload_lds16(b1src + ko, ldsB1);
        __syncthreads();                 // drains vmcnt: staging complete

        half8 aF[4], bF[4];
        #pragma unroll
        for (int mi = 0; mi < 4; ++mi)
            aF[mi] = ld8h(lds + aoff + mi * 512);
        #pragma unroll
        for (int ni = 0; ni < 4; ++ni)
            bF[ni] = ld8h(lds + boff + ni * 512);
        #pragma unroll
        for (int mi = 0; mi < 4; ++mi)
            #pragma unroll
            for (int ni = 0; ni < 4; ++ni)
                acc[mi][ni] = __builtin_amdgcn_mfma_f32_16x16x32_f16(aF[mi], bF[ni], acc[mi][ni], 0, 0, 0);
        __syncthreads();                 // buffer free for next stage
    }

    // ---- epilogue (round-14): tracked argmin, dist^2-bit packing ----
    float q2v[4];
    #pragma unroll
    for (int ni = 0; ni < 4; ++ni)
        q2v[ni] = sq2[j0b + wc * 64 + ni * 16 + lrow];
    float4 q1v[4];
    #pragma unroll
    for (int mi = 0; mi < 4; ++mi)
        q1v[mi] = *(const float4*)(sq1 + i0b + wr * 64 + mi * 16 + 4 * lg);

    float    cmin[4];
    unsigned cidx[4];
    #pragma unroll
    for (int ni = 0; ni < 4; ++ni) { cmin[ni] = __uint_as_float(0x7F800000u); cidx[ni] = 0xFFFFFFFFu; }

    #pragma unroll
    for (int mi = 0; mi < 4; ++mi) {
        const float* q1p = (const float*)&q1v[mi];
        #pragma unroll
        for (int r = 0; r < 4; ++r) {
            const float    q1 = q1p[r];
            const unsigned irow = (unsigned)(i0b + wr * 64 + mi * 16 + 4 * lg + r);
            float    rbest = 0.f;
            unsigned rbn = 0;
            #pragma unroll
            for (int ni = 0; ni < 4; ++ni) {
                float d = acc[mi][ni][r];
                float t = fmaf(-2.f, d, q2v[ni]);
                float c = fmaf(-2.f, d, q1);
                if (ni == 0) { rbest = t; }
                else if (t < rbest) { rbest = t; rbn = (unsigned)ni; }
                if (c < cmin[ni]) { cmin[ni] = c; cidx[ni] = irow; }
            }
            float g = rbest;
            #pragma unroll
            for (int mask = 8; mask; mask >>= 1)
                g = fminf(g, __shfl_xor(g, mask));
            unsigned jc = (rbest == g)
                ? (unsigned)(j0b + wc * 64 + rbn * 16 + lrow) : 0xFFFFFFFFu;
            #pragma unroll
            for (int mask = 8; mask; mask >>= 1)
                jc = umin32(jc, (unsigned)__shfl_xor((int)jc, mask));
            if (lrow == 0) {
                float d2 = g + q1;
                u64 pk = ((u64)__float_as_uint(d2) << 32) | jc;
                atomicMin(&rowmin[irow], pk);
            }
        }
    }
    #pragma unroll
    for (int ni = 0; ni < 4; ++ni) {
        float d2 = cmin[ni] + q2v[ni];
        u64 pk = ((u64)__float_as_uint(d2) << 32) | cidx[ni];
        pk = umin64(pk, __shfl_xor(pk, 16));
        pk = umin64(pk, __shfl_xor(pk, 32));
        if (lane < 16)
            atomicMin(&colmin[j0b + wc * 64 + ni * 16 + lrow], pk);
    }
}

// ============================ fallback path ============================
// In-kernel bf16 3-way split LDS version; dist^2-bit packing.
__global__ __launch_bounds__(256) void mfma_tile_kernel(
    const float* __restrict__ d1, const float* __restrict__ d2,
    const float* __restrict__ sq1, const float* __restrict__ sq2,
    u64* __restrict__ rowmin, u64* __restrict__ colmin)
{
    __shared__ __align__(16) short lds[6 * 4096];
    const int tid = threadIdx.x;
    const int i0b = blockIdx.y * 128;
    const int j0b = blockIdx.x * 128;
    const int srow  = tid >> 1;
    const int shalf = tid & 1;
    const int sfr   = fswz(srow);
    const int sg0   = ((2 * shalf) ^ sfr) * 8;
    const int sg1   = ((2 * shalf + 1) ^ sfr) * 8;
    const float* gA = d1 + (size_t)(i0b + srow) * DD + shalf * 16;
    const float* gB = d2 + (size_t)(j0b + srow) * DD + shalf * 16;
    short* wA = lds + srow * 32;
    short* wB = lds + 3 * 4096 + srow * 32;
    const int lane = tid & 63;
    const int wid  = tid >> 6;
    const int wr   = wid >> 1;
    const int wc   = wid & 1;
    const int lrow = lane & 15;
    const int lg   = lane >> 4;
    const int gx   = (lg ^ fswz(lrow)) * 8;
    const int aoff = (wr * 64 + lrow) * 32 + gx;
    const int boff = 3 * 4096 + (wc * 64 + lrow) * 32 + gx;

    f32x4 acc[4][4];
    #pragma unroll
    for (int mi = 0; mi < 4; ++mi)
        #pragma unroll
        for (int ni = 0; ni < 4; ++ni)
            acc[mi][ni] = (f32x4){0.f, 0.f, 0.f, 0.f};

    for (int kc = 0; kc < 4; ++kc) {
        {
            const float* sp = gA + kc * 32;
            short8 H0, M0, L0, H1, M1, L1;
            #pragma unroll
            for (int e = 0; e < 8; ++e) {
                float x = sp[e];
                ushort_t h = bf_rn(x); float r1 = x - bf_up(h);
                ushort_t m = bf_rn(r1); float r2 = r1 - bf_up(m);
                H0[e] = (short)h; M0[e] = (short)m; L0[e] = (short)bf_rn(r2);
            }
            #pragma unroll
            for (int e = 0; e < 8; ++e) {
                float x = sp[8 + e];
                ushort_t h = bf_rn(x); float r1 = x - bf_up(h);
                ushort_t m = bf_rn(r1); float r2 = r1 - bf_up(m);
                H1[e] = (short)h; M1[e] = (short)m; L1[e] = (short)bf_rn(r2);
            }
            *(short8*)(wA + sg0)        = H0;
            *(short8*)(wA + sg1)        = H1;
            *(short8*)(wA + 4096 + sg0) = M0;
            *(short8*)(wA + 4096 + sg1) = M1;
            *(short8*)(wA + 8192 + sg0) = L0;
            *(short8*)(wA + 8192 + sg1) = L1;
        }
        {
            const float* sp = gB + kc * 32;
            short8 H0, M0, L0, H1, M1, L1;
            #pragma unroll
            for (int e = 0; e < 8; ++e) {
                float x = sp[e];
                ushort_t h = bf_rn(x); float r1 = x - bf_up(h);
                ushort_t m = bf_rn(r1); float r2 = r1 - bf_up(m);
                H0[e] = (short)h; M0[e] = (short)m; L0[e] = (short)bf_rn(r2);
            }
            #pragma unroll
            for (int e = 0; e < 8; ++e) {
                float x = sp[8 + e];
                ushort_t h = bf_rn(x); float r1 = x - bf_up(h);
                ushort_t m = bf_rn(r1); float r2 = r1 - bf_up(m);
                H1[e] = (short)h; M1[e] = (short)m; L1[e] = (short)bf_rn(r2);
            }
            *(short8*)(wB + sg0)        = H0;
            *(short8*)(wB + sg1)        = H1;
            *(short8*)(wB + 4096 + sg0) = M0;
            *(short8*)(wB + 4096 + sg1) = M1;
            *(short8*)(wB + 8192 + sg0) = L0;
            *(short8*)(wB + 8192 + sg1) = L1;
        }
        __syncthreads();
        short8 af[3][4], bfr[3][4];
        #pragma unroll
        for (int c = 0; c < 3; ++c)
            #pragma unroll
            for (int t = 0; t < 4; ++t) {
                af[c][t]  = *(const short8*)(lds + c * 4096 + aoff + t * 512);
                bfr[c][t] = *(const short8*)(lds + c * 4096 + boff + t * 512);
            }
        #pragma unroll
        for (int mi = 0; mi < 4; ++mi)
            #pragma unroll
            for (int ni = 0; ni < 4; ++ni) {
                f32x4 a = acc[mi][ni];
                a = __builtin_amdgcn_mfma_f32_16x16x32_bf16(af[0][mi], bfr[0][ni], a, 0, 0, 0);
                a = __builtin_amdgcn_mfma_f32_16x16x32_bf16(af[0][mi], bfr[1][ni], a, 0, 0, 0);
                a = __builtin_amdgcn_mfma_f32_16x16x32_bf16(af[1][mi], bfr[0][ni], a, 0, 0, 0);
                a = __builtin_amdgcn_mfma_f32_16x16x32_bf16(af[0][mi], bfr[2][ni], a, 0, 0, 0);
                a = __builtin_amdgcn_mfma_f32_16x16x32_bf16(af[1][mi], bfr[1][ni], a, 0, 0, 0);
                a = __builtin_amdgcn_mfma_f32_16x16x32_bf16(af[2][mi], bfr[0][ni], a, 0, 0, 0);
                acc[mi][ni] = a;
            }
        __syncthreads();
    }

    float q2v[4];
    #pragma unroll
    for (int ni = 0; ni < 4; ++ni)
        q2v[ni] = sq2[j0b + wc * 64 + ni * 16 + lrow];
    float4 q1v[4];
    #pragma unroll
    for (int mi = 0; mi < 4; ++mi)
        q1v[mi] = *(const float4*)(sq1 + i0b + wr * 64 + mi * 16 + 4 * lg);

    float    cmin[4];
    unsigned cidx[4];
    #pragma unroll
    for (int ni = 0; ni < 4; ++ni) { cmin[ni] = __uint_as_float(0x7F800000u); cidx[ni] = 0xFFFFFFFFu; }

    #pragma unroll
    for (int mi = 0; mi < 4; ++mi) {
        const float* q1p = (const float*)&q1v[mi];
        #pragma unroll
        for (int r = 0; r < 4; ++r) {
            const float    q1 = q1p[r];
            const unsigned irow = (unsigned)(i0b + wr * 64 + mi * 16 + 4 * lg + r);
            float    rbest = 0.f;
            unsigned rbn = 0;
            #pragma unroll
            for (int ni = 0; ni < 4; ++ni) {
                float d = acc[mi][ni][r];
                float t = fmaf(-2.f, d, q2v[ni]);
                float c = fmaf(-2.f, d, q1);
                if (ni == 0) { rbest = t; }
                else if (t < rbest) { rbest = t; rbn = (unsigned)ni; }
                if (c < cmin[ni]) { cmin[ni] = c; cidx[ni] = irow; }
            }
            float g = rbest;
            #pragma unroll
            for (int mask = 8; mask; mask >>= 1)
                g = fminf(g, __shfl_xor(g, mask));
            unsigned jc = (rbest == g)
                ? (unsigned)(j0b + wc * 64 + rbn * 16 + lrow) : 0xFFFFFFFFu;
            #pragma unroll
            for (int mask = 8; mask; mask >>= 1)
                jc = umin32(jc, (unsigned)__shfl_xor((int)jc, mask));
            if (lrow == 0) {
                float d2 = g + q1;
                u64 pk = ((u64)__float_as_uint(d2) << 32) | jc;
                atomicMin(&rowmin[irow], pk);
            }
        }
    }
    #pragma unroll
    for (int ni = 0; ni < 4; ++ni) {
        float d2 = cmin[ni] + q2v[ni];
        u64 pk = ((u64)__float_as_uint(d2) << 32) | cidx[ni];
        pk = umin64(pk, __shfl_xor(pk, 16));
        pk = umin64(pk, __shfl_xor(pk, 32));
        if (lane < 16)
            atomicMin(&colmin[j0b + wc * 64 + ni * 16 + lrow], pk);
    }
}

// Kernel 3: assemble outputs. rowmin/colmin hold (dist^2 bits << 32) | idx.
// Non-mutual rows get bigf() instead of +inf (inf-inf = NaN fails diff).
__global__ __launch_bounds__(256) void final_kernel(
    const u64* __restrict__ rowmin, const u64* __restrict__ colmin,
    float* __restrict__ out) {
    int i = blockIdx.x * 256 + threadIdx.x;
    if (i >= NB1) return;
    u64 rm = rowmin[i];
    unsigned ju = (unsigned)(rm & 0xFFFFFFFFu);
    float d2 = __uint_as_float((unsigned)(rm >> 32));
    float dist = sqrtf(fmaxf(d2, 0.f));
    dist = fminf(dist, bigf());
    bool valid = (ju < (unsigned)NB2);
    int j = valid ? (int)ju : 0;
    u64 cm = colmin[j];
    int i2 = (int)(cm & 0xFFFFFFFFu);
    bool mut = valid && (i2 == i);
    out[i] = mut ? dist : bigf();
    out[NB1 + 2 * i]     = mut ? (float)i : -1.f;
    out[NB1 + 2 * i + 1] = mut ? (float)j : -1.f;
    out[NB1 + 2 * NB1 + i] = mut ? 1.f : 0.f;
}

extern "C" void kernel_launch(void* const* d_in, const int* in_sizes, int n_in,
                              void* d_out, int out_size, void* d_ws, size_t ws_size,
                              hipStream_t stream) {
    const float* d1 = (const float*)d_in[0];
    const float* d2 = (const float*)d_in[1];
    float* out = (float*)d_out;

    char* ws = (char*)d_ws;
    float* sq1    = (float*)(ws);
    float* sq2    = (float*)(ws + 32768);
    u64*   rowmin = (u64*)(ws + 81920);
    u64*   colmin = (u64*)(ws + 147456);
    _Float16* Ap = (_Float16*)(ws + 245760);            // 8192*384*2  = 6,291,456 B
    _Float16* Bp = (_Float16*)(ws + 245760 + 6291456);  // 12288*384*2 = 9,437,184 B
    const size_t need = 245760 + 6291456 + 9437184;     // ~15.2 MB

    hipLaunchKernelGGL(prep_kernel, dim3((NB2 + 255) / 256), dim3(256), 0, stream,
                       d1, d2, sq1, sq2, rowmin, colmin);
    if (ws_size >= need) {
        hipLaunchKernelGGL(split_kcat16_kernel, dim3(320), dim3(256), 0, stream,
                           d1, d2, Ap, Bp);
        hipLaunchKernelGGL(mfma_lds9_kernel, dim3(6144), dim3(256), 0, stream,
                           Ap, Bp, sq1, sq2, rowmin, colmin);
    } else {
        hipLaunchKernelGGL(mfma_tile_kernel, dim3(NB2 / 128, NB1 / 128), dim3(256), 0, stream,
                           d1, d2, sq1, sq2, rowmin, colmin);
    }
    hipLaunchKernelGGL(final_kernel, dim3((NB1 + 255) / 256), dim3(256), 0, stream,
                       rowmin, colmin, out);
}